// Round 7
// baseline (206.612 us; speedup 1.0000x reference)
//
#include <hip/hip_runtime.h>

// TemporalMambaBlock: B=2,T=16,H=W=28,C=192; D_inner=384, d_state=16, dt_rank=12, d_conv=4
#define NSEQ 1568
#define TDIM 16
#define CDIM 192
#define DIN  384
#define SDIM 16
#define RNK  12
#define XZW  768
#define DBLW 44
#define HW784 784

// padded LDS strides (halves): row stride dwords mod 32 == 4 -> b128 quad reads 2-way (free)
#define XNP  200   // xn rows (192 + 8 pad)
#define DINP 392   // u / z rows (384 + 8)
#define DBLP 48    // dbl rows (44 -> 48, f32)

// packed-weight tiling. Fragment layout (lane, j=0..7):
//   packed[((nt*KT + kt)*64 + lane)*8 + j] = W[kt*32 + (lane>>4)*8 + j][nt*16 + (lane&15)]
// Used as the *A* operand (A[m=lane&15 -> out-channel][k=quad*8+j]) = W^T tile.
#define NT_IN 48
#define KT_IN 6
#define NT_OUT 12
#define KT_OUT 12
#define NT_XP 3
#define KT_XP 12
#define GRP_IN  (NT_IN*KT_IN*64)    // 18432 groups of 8
#define GRP_OUT (NT_OUT*KT_OUT*64)  // 9216
#define GRP_XP  (NT_XP*KT_XP*64)    // 2304
#define OFF_OUT (GRP_IN*8)
#define OFF_XP  (OFF_OUT + GRP_OUT*8)
#define WS_ELEMS (OFF_XP + GRP_XP*8)   // 239616 u16

#define IN_EL  (CDIM*XZW)   // 147456
#define OUT_EL (DIN*CDIM)   // 73728
#define XP_EL  (GRP_XP*8)   // 18432 (packed space, incl. pad)
#define PACK_TOT (IN_EL + OUT_EL + XP_EL)

typedef unsigned short u16;
typedef unsigned int   u32;
typedef __attribute__((ext_vector_type(8))) short short8;
typedef __attribute__((ext_vector_type(4))) float f32x4;
typedef __attribute__((ext_vector_type(2))) unsigned int u32x2;

#define LOG2E 1.44269504f
#define LN2   0.69314718f

// packed weights: module device global — same bytes every call, ordered vs the
// consumer by the same-stream kernel boundary (release/acquire). Never poisoned.
__device__ __align__(16) u16 g_ws[WS_ELEMS];

__device__ __forceinline__ float bf2f(u16 u) {
  union { u32 i; float f; } c; c.i = ((u32)u) << 16; return c.f;
}
__device__ __forceinline__ u16 f2bf(float f) {   // round-to-nearest-even
  union { float f; u32 i; } c; c.f = f;
  u32 i = c.i;
  i += 0x7FFFu + ((i >> 16) & 1u);
  return (u16)(i >> 16);
}

__device__ __forceinline__ float ex2(float x) {
#if __has_builtin(__builtin_amdgcn_exp2f)
  return __builtin_amdgcn_exp2f(x);
#else
  return exp2f(x);
#endif
}
__device__ __forceinline__ float lg2(float x) {
#if __has_builtin(__builtin_amdgcn_logf)
  return __builtin_amdgcn_logf(x);
#else
  return log2f(x);
#endif
}
__device__ __forceinline__ float frcp(float x) {
#if __has_builtin(__builtin_amdgcn_rcpf)
  return __builtin_amdgcn_rcpf(x);
#else
  return 1.0f / x;
#endif
}
__device__ __forceinline__ float sigmoid_f(float s) {       // 1/(1+e^-s)
  return frcp(1.0f + ex2(-LOG2E * s));
}
__device__ __forceinline__ float softplus_f(float a) {      // log(1+e^a), stable
  return fmaxf(a, 0.f) + LN2 * lg2(1.0f + ex2(-LOG2E * fabsf(a)));
}

template<bool B16>
__device__ __forceinline__ float ldg(const void* p, int i) {
  if (B16) return bf2f(((const u16*)p)[i]);
  return ((const float*)p)[i];
}
// 4-consecutive-element vector load/store (i multiple of 4)
template<bool B16>
__device__ __forceinline__ f32x4 ld4(const void* p, int i) {
  f32x4 r;
  if (B16) {
    u32x2 raw = *(const u32x2*)((const u16*)p + i);
    r[0] = bf2f((u16)(raw[0] & 0xFFFF)); r[1] = bf2f((u16)(raw[0] >> 16));
    r[2] = bf2f((u16)(raw[1] & 0xFFFF)); r[3] = bf2f((u16)(raw[1] >> 16));
  } else {
    r = *(const f32x4*)((const float*)p + i);
  }
  return r;
}
template<bool B16>
__device__ __forceinline__ void st4(void* p, int i, f32x4 v) {
  if (B16) {
    u32x2 o;
    o[0] = ((u32)f2bf(v[1]) << 16) | f2bf(v[0]);
    o[1] = ((u32)f2bf(v[3]) << 16) | f2bf(v[2]);
    *(u32x2*)((u16*)p + i) = o;
  } else {
    *(f32x4*)((float*)p + i) = v;
  }
}

// dtype probe: bf16 data has plausible exponents at even u16 slots; f32 read
// as u16 gives mantissa noise. (Rounds 2-5: selects the f32 path.)
__device__ __forceinline__ bool probe_bf16(const void* x) {
  const u16* xu = (const u16*)x;
  int plaus = 0;
  #pragma unroll
  for (int k = 0; k < 32; ++k) {
    u16 v = xu[2*k];
    int e = (v >> 7) & 0xFF;
    plaus += ((e >= 100 && e <= 140) || v == 0) ? 1 : 0;
  }
  return plaus >= 16;
}

// ---------------- weight packing: element-wise, coalesced reads -------------
template<bool B16>
__device__ __forceinline__ void pack_body(const void* in_w, const void* out_w,
                                          const void* xp_w, int e) {
  if (e < IN_EL) {
    int k = e / XZW, n = e - k*XZW;
    int nt = n >> 4, l16 = n & 15, kt = k >> 5, q8 = (k & 31) >> 3, j = k & 7;
    int lane = q8*16 + l16;
    g_ws[((nt*KT_IN + kt)*64 + lane)*8 + j] = f2bf(ldg<B16>(in_w, e));
  } else if (e < IN_EL + OUT_EL) {
    int ee = e - IN_EL;
    int k = ee / CDIM, n = ee - k*CDIM;
    int nt = n >> 4, l16 = n & 15, kt = k >> 5, q8 = (k & 31) >> 3, j = k & 7;
    int lane = q8*16 + l16;
    g_ws[OFF_OUT + ((nt*KT_OUT + kt)*64 + lane)*8 + j] = f2bf(ldg<B16>(out_w, ee));
  } else if (e < PACK_TOT) {             // xp: iterate packed space (handles pad)
    int ee = e - IN_EL - OUT_EL;
    int gg = ee >> 3, j = ee & 7;
    int lane = gg & 63, kt = (gg >> 6) % KT_XP, nt = gg / (64*KT_XP);
    int k = kt*32 + (lane >> 4)*8 + j, n = nt*16 + (lane & 15);
    g_ws[OFF_XP + ee] = f2bf(n < DBLW ? ldg<B16>(xp_w, k*DBLW + n) : 0.f);
  }
}

__global__ void pack_w(const void* __restrict__ x, const void* __restrict__ in_w,
                       const void* __restrict__ out_w, const void* __restrict__ xp_w) {
  int e = blockIdx.x * blockDim.x + threadIdx.x;
  if (e < PACK_TOT) {
    if (probe_bf16(x)) pack_body<true >(in_w, out_w, xp_w, e);
    else               pack_body<false>(in_w, out_w, xp_w, e);
  }
}

// ---------------- fused MFMA kernel -----------------------------------------
struct Smem {
  float dbl[TDIM*DBLP];   // x_proj out: dt_low|B|C        3072 B
  u16   xn [TDIM*XNP];    // rmsnormed, padded             6400 B
  u16   u  [TDIM*DINP];   // u -> uc (in-place), padded   12544 B
  u16   z  [TDIM*DINP];   // z -> gated y (in-place)      12544 B
};                        // total 34,560 B -> 4 blocks/CU

template<bool B16>
__device__ __forceinline__ void body(
    Smem& sm,
    const void* __restrict__ x,        const void* __restrict__ norm_w,
    const void* __restrict__ conv_w,   const void* __restrict__ conv_b,
    const void* __restrict__ dt_proj_w,const void* __restrict__ dt_proj_b,
    const void* __restrict__ A_log,    const void* __restrict__ Dp,
    void* __restrict__ out)
{
  const int tid  = threadIdx.x;
  const int wid  = tid >> 6;
  const int lane = tid & 63;
  const int quad = lane >> 4;
  const int l16  = lane & 15;
  const u16* ws = g_ws;
  const int n  = blockIdx.x;
  const int b  = n / HW784;
  const int hw = n - b * HW784;

  // ---- per-thread (channel d = tid) params ----
  float cw0 = ldg<B16>(conv_w, tid*4+0), cw1 = ldg<B16>(conv_w, tid*4+1);
  float cw2 = ldg<B16>(conv_w, tid*4+2), cw3 = ldg<B16>(conv_w, tid*4+3);
  float cbias = ldg<B16>(conv_b, tid);
  float wd[RNK];
  float dt_bias = ldg<B16>(dt_proj_b, tid);
  #pragma unroll
  for (int r = 0; r < RNK; ++r) wd[r] = ldg<B16>(dt_proj_w, r*DIN + tid);
  float Dv = ldg<B16>(Dp, tid);
  // geometric-A detection: A[s] = -exp(A_log[s]); geo iff A[s] == (s+1)*A[0]
  float a2 = -LOG2E * ex2(LOG2E * ldg<B16>(A_log, tid*SDIM + 0));  // LOG2E*A[0]
  bool geo = true;
  #pragma unroll
  for (int s = 1; s < SDIM; ++s) {
    float as = -LOG2E * ex2(LOG2E * ldg<B16>(A_log, tid*SDIM + s));
    geo = geo && (fabsf(as - (float)(s+1)*a2) <= 1e-4f * fabsf(as) + 1e-30f);
  }

  // ---- P1: RMSNorm straight from global (192 = 3 x 64 lanes) -> xn ----
  {
    const int c0 = lane, c1 = lane + 64, c2 = lane + 128;
    float nw0 = ldg<B16>(norm_w, c0), nw1 = ldg<B16>(norm_w, c1), nw2 = ldg<B16>(norm_w, c2);
    for (int t = wid; t < TDIM; t += 6) {
      int base = ((b*TDIM + t)*HW784 + hw)*CDIM;
      float v0 = ldg<B16>(x, base + c0);
      float v1 = ldg<B16>(x, base + c1);
      float v2 = ldg<B16>(x, base + c2);
      float ss = v0*v0 + v1*v1 + v2*v2;
      #pragma unroll
      for (int off = 32; off > 0; off >>= 1) ss += __shfl_xor(ss, off, 64);
      float rs = rsqrtf(ss * (1.0f/CDIM) + 1e-6f);
      sm.xn[t*XNP + c0] = f2bf(v0 * rs * nw0);
      sm.xn[t*XNP + c1] = f2bf(v1 * rs * nw1);
      sm.xn[t*XNP + c2] = f2bf(v2 * rs * nw2);
    }
  }
  __syncthreads();

  // ---- P2: in_proj via MFMA (W^T as A, Xn^T as B -> D rows=channels, cols=t) ----
  {
    short8 xfr[KT_IN];   // activation fragments (B operand): Xn[t=l16][kt*32+quad*8..+7]
    #pragma unroll
    for (int kt = 0; kt < KT_IN; ++kt)
      xfr[kt] = *(const short8*)(sm.xn + l16*XNP + kt*32 + quad*8);
    #pragma unroll
    for (int g = 0; g < 2; ++g) {
      f32x4 acc[4];
      #pragma unroll
      for (int i = 0; i < 4; ++i) acc[i] = (f32x4)0.f;
      #pragma unroll
      for (int kt = 0; kt < KT_IN; ++kt) {
        #pragma unroll
        for (int i = 0; i < 4; ++i) {
          int ntg = wid*8 + g*4 + i;
          short8 wfr = *(const short8*)(ws + ((ntg*KT_IN + kt)*64 + lane)*8);
          acc[i] = __builtin_amdgcn_mfma_f32_16x16x32_bf16(wfr, xfr[kt], acc[i], 0, 0, 0);
        }
      }
      #pragma unroll
      for (int i = 0; i < 4; ++i) {
        int ntg = wid*8 + g*4 + i;
        u16* dst  = (ntg < 24) ? sm.u : sm.z;
        int col0  = ((ntg < 24) ? ntg*16 : (ntg-24)*16) + quad*4;  // 4 consecutive channels
        u32x2 o;
        o[0] = ((u32)f2bf(acc[i][1]) << 16) | f2bf(acc[i][0]);
        o[1] = ((u32)f2bf(acc[i][3]) << 16) | f2bf(acc[i][2]);
        *(u32x2*)(dst + l16*DINP + col0) = o;    // t=l16 row, b64 write
      }
    }
  }
  __syncthreads();

  // ---- P3: causal depthwise conv (k=4) + SiLU; keep uc in registers ----
  float uvr[TDIM];
  {
    const int d = tid;
    float um1 = 0.f, um2 = 0.f, um3 = 0.f;
    #pragma unroll
    for (int t = 0; t < TDIM; ++t) {
      float cur = bf2f(sm.u[t*DINP + d]);
      float s = cbias + cur*cw3 + um1*cw2 + um2*cw1 + um3*cw0;
      um3 = um2; um2 = um1; um1 = cur;
      float v = s * sigmoid_f(s);
      uvr[t] = v;
      sm.u[t*DINP + d] = f2bf(v);   // for P4 B-fragments
    }
  }
  __syncthreads();

  // ---- P4: x_proj via MFMA (xp_w^T as A, uc^T as B): waves 0..2 ----
  if (wid < 3) {
    f32x4 acc = (f32x4)0.f;
    #pragma unroll
    for (int kt = 0; kt < KT_XP; ++kt) {
      short8 ufr = *(const short8*)(sm.u + l16*DINP + kt*32 + quad*8);
      short8 wfr = *(const short8*)(ws + OFF_XP + ((wid*KT_XP + kt)*64 + lane)*8);
      acc = __builtin_amdgcn_mfma_f32_16x16x32_bf16(wfr, ufr, acc, 0, 0, 0);
    }
    // dbl[t=l16][feat = wid*16 + quad*4 + r]: 4 consecutive f32 -> b128
    *(f32x4*)(sm.dbl + l16*DBLP + wid*16 + quad*4) = acc;
  }
  __syncthreads();

  // ---- P5: dt_proj + softplus + selective scan + D skip + SiLU(z) gating ----
  {
    const int d = tid;
    float h[SDIM];
    #pragma unroll
    for (int s = 0; s < SDIM; ++s) h[s] = 0.f;
    if (geo) {
      for (int t = 0; t < TDIM; ++t) {
        const float* row = sm.dbl + t*DBLP;
        f32x4 d0 = *(const f32x4*)(row + 0);
        f32x4 d1 = *(const f32x4*)(row + 4);
        f32x4 d2 = *(const f32x4*)(row + 8);
        float a = dt_bias
          + d0[0]*wd[0] + d0[1]*wd[1] + d0[2]*wd[2]  + d0[3]*wd[3]
          + d1[0]*wd[4] + d1[1]*wd[5] + d1[2]*wd[6]  + d1[3]*wd[7]
          + d2[0]*wd[8] + d2[1]*wd[9] + d2[2]*wd[10] + d2[3]*wd[11];
        float dtv = softplus_f(a);
        float uv  = uvr[t];
        float du  = dtv * uv;
        float q = ex2(dtv * a2);               // dA[0] = exp(dt*A[0])
        float Pq[SDIM];                        // Pq[s] = q^(s+1), log-depth tree
        Pq[0] = q;        Pq[1] = q*q;         Pq[2] = Pq[1]*q;     Pq[3] = Pq[1]*Pq[1];
        Pq[4] = Pq[3]*q;  Pq[5] = Pq[3]*Pq[1]; Pq[6] = Pq[3]*Pq[2]; Pq[7] = Pq[3]*Pq[3];
        Pq[8] = Pq[7]*q;  Pq[9] = Pq[7]*Pq[1]; Pq[10]= Pq[7]*Pq[2]; Pq[11]= Pq[7]*Pq[3];
        Pq[12]= Pq[7]*Pq[4]; Pq[13]= Pq[7]*Pq[5]; Pq[14]= Pq[7]*Pq[6]; Pq[15]= Pq[7]*Pq[7];
        float y = 0.f;
        #pragma unroll
        for (int g = 0; g < 4; ++g) {
          f32x4 Bv = *(const f32x4*)(row + 12 + 4*g);
          f32x4 Cv = *(const f32x4*)(row + 28 + 4*g);
          #pragma unroll
          for (int j = 0; j < 4; ++j) {
            int s = 4*g + j;
            h[s] = h[s]*Pq[s] + du*Bv[j];
            y += h[s]*Cv[j];
          }
        }
        y += uv * Dv;
        float zv = bf2f(sm.z[t*DINP + d]);
        sm.z[t*DINP + d] = f2bf(y * (zv * sigmoid_f(zv)));
      }
    } else {
      // cold path (A_log not geometric): reloads A each step
      for (int t = 0; t < TDIM; ++t) {
        const float* row = sm.dbl + t*DBLP;
        float a = dt_bias;
        #pragma unroll
        for (int r = 0; r < RNK; ++r) a += row[r] * wd[r];
        float dtv = softplus_f(a);
        float uv  = uvr[t];
        float du  = dtv * uv;
        float y = 0.f;
        #pragma unroll
        for (int s = 0; s < SDIM; ++s) {
          float As = -LOG2E * ex2(LOG2E * ldg<B16>(A_log, d*SDIM + s));
          float dA = ex2(dtv * As);
          h[s] = h[s]*dA + du * row[12 + s];
          y += h[s] * row[28 + s];
        }
        y += uv * Dv;
        float zv = bf2f(sm.z[t*DINP + d]);
        sm.z[t*DINP + d] = f2bf(y * (zv * sigmoid_f(zv)));
      }
    }
  }
  __syncthreads();

  // ---- P6: out_proj via MFMA (out_w^T as A, y^T as B) + residual ----
  {
    f32x4 acc[2];
    acc[0] = (f32x4)0.f; acc[1] = (f32x4)0.f;
    #pragma unroll
    for (int kt = 0; kt < KT_OUT; ++kt) {
      short8 yfr = *(const short8*)(sm.z + l16*DINP + kt*32 + quad*8);
      #pragma unroll
      for (int i = 0; i < 2; ++i) {
        int ntg = wid*2 + i;
        short8 wfr = *(const short8*)(ws + OFF_OUT + ((ntg*KT_OUT + kt)*64 + lane)*8);
        acc[i] = __builtin_amdgcn_mfma_f32_16x16x32_bf16(wfr, yfr, acc[i], 0, 0, 0);
      }
    }
    #pragma unroll
    for (int i = 0; i < 2; ++i) {
      int c0 = (wid*2 + i)*16 + quad*4;    // 4 consecutive output channels
      int t  = l16;
      int gi = ((b*TDIM + t)*HW784 + hw)*CDIM + c0;
      f32x4 xv = ld4<B16>(x, gi);
      f32x4 o;
      #pragma unroll
      for (int r = 0; r < 4; ++r) o[r] = xv[r] + acc[i][r];
      st4<B16>(out, gi, o);
    }
  }
}

__launch_bounds__(384, 6)   // 6 waves/EU -> 4 blocks/CU; caps VGPR at ~85
__global__ void mamba_mfma(
    const void* __restrict__ x,        const void* __restrict__ norm_w,
    const void* __restrict__ conv_w,   const void* __restrict__ conv_b,
    const void* __restrict__ dt_w,     const void* __restrict__ dt_b,
    const void* __restrict__ A_log,    const void* __restrict__ Dp,
    void* __restrict__ out)
{
  __shared__ Smem sm;
  if (probe_bf16(x))
    body<true >(sm, x, norm_w, conv_w, conv_b, dt_w, dt_b, A_log, Dp, out);
  else
    body<false>(sm, x, norm_w, conv_w, conv_b, dt_w, dt_b, A_log, Dp, out);
}

extern "C" void kernel_launch(void* const* d_in, const int* in_sizes, int n_in,
                              void* d_out, int out_size, void* d_ws, size_t ws_size,
                              hipStream_t stream) {
  pack_w<<<(PACK_TOT + 255) / 256, 256, 0, stream>>>(
      d_in[0], d_in[2], d_in[10], d_in[5]);
  mamba_mfma<<<NSEQ, 384, 0, stream>>>(
      d_in[0], d_in[1], d_in[3], d_in[4],
      d_in[6], d_in[7], d_in[8], d_in[9], d_out);
}

// Round 8
// 200.608 us; speedup vs baseline: 1.0299x; 1.0299x over previous
//
#include <hip/hip_runtime.h>

// TemporalMambaBlock: B=2,T=16,H=W=28,C=192; D_inner=384, d_state=16, dt_rank=12, d_conv=4
#define NSEQ 1568
#define TDIM 16
#define CDIM 192
#define DIN  384
#define SDIM 16
#define RNK  12
#define XZW  768
#define DBLW 44
#define HW784 784

// padded LDS strides (halves): row stride dwords mod 32 == 4 -> b128 quad reads 2-way (free)
#define XNP  200   // xn rows (192 + 8 pad)
#define DINP 392   // u / z rows (384 + 8)
#define DBLP 48    // dbl rows (44 -> 48, f32)

// packed-weight tiling. Fragment layout (lane, j=0..7):
//   packed[((nt*KT + kt)*64 + lane)*8 + j] = W[kt*32 + (lane>>4)*8 + j][nt*16 + (lane&15)]
// Layout is operand-symmetric: usable as B (B[k=quad*8+j][n=l16], rounds 3-5 proven)
// or as A (A[m=l16][k=quad*8+j] = W^T tile, round-7 P2).
#define NT_IN 48
#define KT_IN 6
#define NT_OUT 12
#define KT_OUT 12
#define NT_XP 3
#define KT_XP 12
#define GRP_IN  (NT_IN*KT_IN*64)    // 18432 groups of 8
#define GRP_OUT (NT_OUT*KT_OUT*64)  // 9216
#define GRP_XP  (NT_XP*KT_XP*64)    // 2304
#define OFF_OUT (GRP_IN*8)
#define OFF_XP  (OFF_OUT + GRP_OUT*8)
#define WS_ELEMS (OFF_XP + GRP_XP*8)   // 239616 u16

#define IN_EL  (CDIM*XZW)   // 147456
#define OUT_EL (DIN*CDIM)   // 73728
#define XP_EL  (GRP_XP*8)   // 18432 (packed space, incl. pad)
#define PACK_TOT (IN_EL + OUT_EL + XP_EL)

typedef unsigned short u16;
typedef unsigned int   u32;
typedef __attribute__((ext_vector_type(8))) short short8;
typedef __attribute__((ext_vector_type(4))) float f32x4;
typedef __attribute__((ext_vector_type(2))) unsigned int u32x2;

#define LOG2E 1.44269504f
#define LN2   0.69314718f

// packed weights: module device global — same bytes every call, ordered vs the
// consumer by the same-stream kernel boundary. Never poisoned by the harness.
__device__ __align__(16) u16 g_ws[WS_ELEMS];

__device__ __forceinline__ float bf2f(u16 u) {
  union { u32 i; float f; } c; c.i = ((u32)u) << 16; return c.f;
}
__device__ __forceinline__ u16 f2bf(float f) {   // round-to-nearest-even
  union { float f; u32 i; } c; c.f = f;
  u32 i = c.i;
  i += 0x7FFFu + ((i >> 16) & 1u);
  return (u16)(i >> 16);
}

__device__ __forceinline__ float ex2(float x) {
#if __has_builtin(__builtin_amdgcn_exp2f)
  return __builtin_amdgcn_exp2f(x);
#else
  return exp2f(x);
#endif
}
__device__ __forceinline__ float lg2(float x) {
#if __has_builtin(__builtin_amdgcn_logf)
  return __builtin_amdgcn_logf(x);
#else
  return log2f(x);
#endif
}
__device__ __forceinline__ float frcp(float x) {
#if __has_builtin(__builtin_amdgcn_rcpf)
  return __builtin_amdgcn_rcpf(x);
#else
  return 1.0f / x;
#endif
}
__device__ __forceinline__ float sigmoid_f(float s) {       // 1/(1+e^-s)
  return frcp(1.0f + ex2(-LOG2E * s));
}
__device__ __forceinline__ float softplus_f(float a) {      // log(1+e^a), stable
  return fmaxf(a, 0.f) + LN2 * lg2(1.0f + ex2(-LOG2E * fabsf(a)));
}

template<bool B16>
__device__ __forceinline__ float ldg(const void* p, int i) {
  if (B16) return bf2f(((const u16*)p)[i]);
  return ((const float*)p)[i];
}
template<bool B16>
__device__ __forceinline__ void stg(void* p, int i, float v) {
  if (B16) ((u16*)p)[i] = f2bf(v);
  else     ((float*)p)[i] = v;
}

// dtype probe: bf16 data has plausible exponents at even u16 slots; f32 read
// as u16 gives mantissa noise. (Rounds 2-7: selects the f32 path.)
__device__ __forceinline__ bool probe_bf16(const void* x) {
  const u16* xu = (const u16*)x;
  int plaus = 0;
  #pragma unroll
  for (int k = 0; k < 32; ++k) {
    u16 v = xu[2*k];
    int e = (v >> 7) & 0xFF;
    plaus += ((e >= 100 && e <= 140) || v == 0) ? 1 : 0;
  }
  return plaus >= 16;
}

// ---------------- weight packing: element-wise, coalesced reads -------------
template<bool B16>
__device__ __forceinline__ void pack_body(const void* in_w, const void* out_w,
                                          const void* xp_w, int e) {
  if (e < IN_EL) {
    int k = e / XZW, n = e - k*XZW;
    int nt = n >> 4, l16 = n & 15, kt = k >> 5, q8 = (k & 31) >> 3, j = k & 7;
    int lane = q8*16 + l16;
    g_ws[((nt*KT_IN + kt)*64 + lane)*8 + j] = f2bf(ldg<B16>(in_w, e));
  } else if (e < IN_EL + OUT_EL) {
    int ee = e - IN_EL;
    int k = ee / CDIM, n = ee - k*CDIM;
    int nt = n >> 4, l16 = n & 15, kt = k >> 5, q8 = (k & 31) >> 3, j = k & 7;
    int lane = q8*16 + l16;
    g_ws[OFF_OUT + ((nt*KT_OUT + kt)*64 + lane)*8 + j] = f2bf(ldg<B16>(out_w, ee));
  } else if (e < PACK_TOT) {             // xp: iterate packed space (handles pad)
    int ee = e - IN_EL - OUT_EL;
    int gg = ee >> 3, j = ee & 7;
    int lane = gg & 63, kt = (gg >> 6) % KT_XP, nt = gg / (64*KT_XP);
    int k = kt*32 + (lane >> 4)*8 + j, n = nt*16 + (lane & 15);
    g_ws[OFF_XP + ee] = f2bf(n < DBLW ? ldg<B16>(xp_w, k*DBLW + n) : 0.f);
  }
}

__global__ void pack_w(const void* __restrict__ x, const void* __restrict__ in_w,
                       const void* __restrict__ out_w, const void* __restrict__ xp_w) {
  int e = blockIdx.x * blockDim.x + threadIdx.x;
  if (e < PACK_TOT) {
    if (probe_bf16(x)) pack_body<true >(in_w, out_w, xp_w, e);
    else               pack_body<false>(in_w, out_w, xp_w, e);
  }
}

// ---------------- fused MFMA kernel -----------------------------------------
struct Smem {
  float dbl[TDIM*DBLP];   // x_proj out: dt_low|B|C        3072 B
  u16   xn [TDIM*XNP];    // rmsnormed, padded             6400 B
  u16   u  [TDIM*DINP];   // u -> uc (in-place), padded   12544 B
  u16   z  [TDIM*DINP];   // z -> gated y (in-place)      12544 B
};                        // total 34,560 B -> 4 blocks/CU

template<bool B16>
__device__ __forceinline__ void body(
    Smem& sm,
    const void* __restrict__ x,        const void* __restrict__ norm_w,
    const void* __restrict__ conv_w,   const void* __restrict__ conv_b,
    const void* __restrict__ dt_proj_w,const void* __restrict__ dt_proj_b,
    const void* __restrict__ A_log,    const void* __restrict__ Dp,
    void* __restrict__ out)
{
  const int tid  = threadIdx.x;
  const int wid  = tid >> 6;
  const int lane = tid & 63;
  const int quad = lane >> 4;
  const int l16  = lane & 15;
  const u16* ws = g_ws;
  const int n  = blockIdx.x;
  const int b  = n / HW784;
  const int hw = n - b * HW784;

  // ---- per-thread (channel d = tid) params ----
  float cw0 = ldg<B16>(conv_w, tid*4+0), cw1 = ldg<B16>(conv_w, tid*4+1);
  float cw2 = ldg<B16>(conv_w, tid*4+2), cw3 = ldg<B16>(conv_w, tid*4+3);
  float cbias = ldg<B16>(conv_b, tid);
  float wd[RNK];
  float dt_bias = ldg<B16>(dt_proj_b, tid);
  #pragma unroll
  for (int r = 0; r < RNK; ++r) wd[r] = ldg<B16>(dt_proj_w, r*DIN + tid);
  float Dv = ldg<B16>(Dp, tid);
  // geometric-A detection: A[s] = -exp(A_log[s]); geo iff A[s] == (s+1)*A[0]
  float a2 = -LOG2E * ex2(LOG2E * ldg<B16>(A_log, tid*SDIM + 0));  // LOG2E*A[0]
  bool geo = true;
  #pragma unroll
  for (int s = 1; s < SDIM; ++s) {
    float as = -LOG2E * ex2(LOG2E * ldg<B16>(A_log, tid*SDIM + s));
    geo = geo && (fabsf(as - (float)(s+1)*a2) <= 1e-4f * fabsf(as) + 1e-30f);
  }

  // ---- P1: RMSNorm straight from global (192 = 3 x 64 lanes) -> xn ----
  {
    const int c0 = lane, c1 = lane + 64, c2 = lane + 128;
    float nw0 = ldg<B16>(norm_w, c0), nw1 = ldg<B16>(norm_w, c1), nw2 = ldg<B16>(norm_w, c2);
    for (int t = wid; t < TDIM; t += 6) {
      int base = ((b*TDIM + t)*HW784 + hw)*CDIM;
      float v0 = ldg<B16>(x, base + c0);
      float v1 = ldg<B16>(x, base + c1);
      float v2 = ldg<B16>(x, base + c2);
      float ss = v0*v0 + v1*v1 + v2*v2;
      #pragma unroll
      for (int off = 32; off > 0; off >>= 1) ss += __shfl_xor(ss, off, 64);
      float rs = rsqrtf(ss * (1.0f/CDIM) + 1e-6f);
      sm.xn[t*XNP + c0] = f2bf(v0 * rs * nw0);
      sm.xn[t*XNP + c1] = f2bf(v1 * rs * nw1);
      sm.xn[t*XNP + c2] = f2bf(v2 * rs * nw2);
    }
  }
  __syncthreads();

  // ---- P2: in_proj via MFMA, swapped operands (W^T as A, Xn^T as B) ----
  // D[m=channel][n=t]: lane holds 4 consecutive channels at t=l16 -> b64 LDS write.
  {
    short8 xfr[KT_IN];   // B operand: Xn[t=l16][kt*32+quad*8..+7]
    #pragma unroll
    for (int kt = 0; kt < KT_IN; ++kt)
      xfr[kt] = *(const short8*)(sm.xn + l16*XNP + kt*32 + quad*8);
    #pragma unroll
    for (int g = 0; g < 2; ++g) {
      f32x4 acc[4];
      #pragma unroll
      for (int i = 0; i < 4; ++i) acc[i] = (f32x4)0.f;
      #pragma unroll
      for (int kt = 0; kt < KT_IN; ++kt) {
        #pragma unroll
        for (int i = 0; i < 4; ++i) {
          int ntg = wid*8 + g*4 + i;
          short8 wfr = *(const short8*)(ws + ((ntg*KT_IN + kt)*64 + lane)*8);
          acc[i] = __builtin_amdgcn_mfma_f32_16x16x32_bf16(wfr, xfr[kt], acc[i], 0, 0, 0);
        }
      }
      #pragma unroll
      for (int i = 0; i < 4; ++i) {
        int ntg = wid*8 + g*4 + i;
        u16* dst  = (ntg < 24) ? sm.u : sm.z;
        int col0  = ((ntg < 24) ? ntg*16 : (ntg-24)*16) + quad*4;  // 4 consecutive channels
        u32x2 o;
        o[0] = ((u32)f2bf(acc[i][1]) << 16) | f2bf(acc[i][0]);
        o[1] = ((u32)f2bf(acc[i][3]) << 16) | f2bf(acc[i][2]);
        *(u32x2*)(dst + l16*DINP + col0) = o;    // t=l16 row, b64 write
      }
    }
  }
  __syncthreads();

  // ---- P3: causal depthwise conv (k=4) + SiLU; keep uc in registers ----
  float uvr[TDIM];
  {
    const int d = tid;
    float um1 = 0.f, um2 = 0.f, um3 = 0.f;
    #pragma unroll
    for (int t = 0; t < TDIM; ++t) {
      float cur = bf2f(sm.u[t*DINP + d]);
      float s = cbias + cur*cw3 + um1*cw2 + um2*cw1 + um3*cw0;
      um3 = um2; um2 = um1; um1 = cur;
      float v = s * sigmoid_f(s);
      uvr[t] = v;
      sm.u[t*DINP + d] = f2bf(v);   // for P4 B-fragments
    }
  }
  __syncthreads();

  // ---- P4: x_proj via MFMA, swapped operands (xp_w^T as A, uc^T as B) ----
  if (wid < 3) {
    f32x4 acc = (f32x4)0.f;
    #pragma unroll
    for (int kt = 0; kt < KT_XP; ++kt) {
      short8 ufr = *(const short8*)(sm.u + l16*DINP + kt*32 + quad*8);
      short8 wfr = *(const short8*)(ws + OFF_XP + ((wid*KT_XP + kt)*64 + lane)*8);
      acc = __builtin_amdgcn_mfma_f32_16x16x32_bf16(wfr, ufr, acc, 0, 0, 0);
    }
    // dbl[t=l16][feat = wid*16 + quad*4 + r]: 4 consecutive f32 -> b128 write
    *(f32x4*)(sm.dbl + l16*DBLP + wid*16 + quad*4) = acc;
  }
  __syncthreads();

  // ---- P5: dt_proj + softplus + selective scan + D skip + SiLU(z) gating ----
  {
    const int d = tid;
    float h[SDIM];
    #pragma unroll
    for (int s = 0; s < SDIM; ++s) h[s] = 0.f;
    if (geo) {
      for (int t = 0; t < TDIM; ++t) {
        const float* row = sm.dbl + t*DBLP;
        f32x4 d0 = *(const f32x4*)(row + 0);
        f32x4 d1 = *(const f32x4*)(row + 4);
        f32x4 d2 = *(const f32x4*)(row + 8);
        float a = dt_bias
          + d0[0]*wd[0] + d0[1]*wd[1] + d0[2]*wd[2]  + d0[3]*wd[3]
          + d1[0]*wd[4] + d1[1]*wd[5] + d1[2]*wd[6]  + d1[3]*wd[7]
          + d2[0]*wd[8] + d2[1]*wd[9] + d2[2]*wd[10] + d2[3]*wd[11];
        float dtv = softplus_f(a);
        float uv  = uvr[t];
        float du  = dtv * uv;
        float q = ex2(dtv * a2);               // dA[0] = exp(dt*A[0])
        float Pq[SDIM];                        // Pq[s] = q^(s+1), log-depth tree
        Pq[0] = q;        Pq[1] = q*q;         Pq[2] = Pq[1]*q;     Pq[3] = Pq[1]*Pq[1];
        Pq[4] = Pq[3]*q;  Pq[5] = Pq[3]*Pq[1]; Pq[6] = Pq[3]*Pq[2]; Pq[7] = Pq[3]*Pq[3];
        Pq[8] = Pq[7]*q;  Pq[9] = Pq[7]*Pq[1]; Pq[10]= Pq[7]*Pq[2]; Pq[11]= Pq[7]*Pq[3];
        Pq[12]= Pq[7]*Pq[4]; Pq[13]= Pq[7]*Pq[5]; Pq[14]= Pq[7]*Pq[6]; Pq[15]= Pq[7]*Pq[7];
        float y = 0.f;
        #pragma unroll
        for (int g = 0; g < 4; ++g) {
          f32x4 Bv = *(const f32x4*)(row + 12 + 4*g);
          f32x4 Cv = *(const f32x4*)(row + 28 + 4*g);
          #pragma unroll
          for (int j = 0; j < 4; ++j) {
            int s = 4*g + j;
            h[s] = h[s]*Pq[s] + du*Bv[j];
            y += h[s]*Cv[j];
          }
        }
        y += uv * Dv;
        float zv = bf2f(sm.z[t*DINP + d]);
        sm.z[t*DINP + d] = f2bf(y * (zv * sigmoid_f(zv)));
      }
    } else {
      // cold path (A_log not geometric): reloads A each step
      for (int t = 0; t < TDIM; ++t) {
        const float* row = sm.dbl + t*DBLP;
        float a = dt_bias;
        #pragma unroll
        for (int r = 0; r < RNK; ++r) a += row[r] * wd[r];
        float dtv = softplus_f(a);
        float uv  = uvr[t];
        float du  = dtv * uv;
        float y = 0.f;
        #pragma unroll
        for (int s = 0; s < SDIM; ++s) {
          float As = -LOG2E * ex2(LOG2E * ldg<B16>(A_log, d*SDIM + s));
          float dA = ex2(dtv * As);
          h[s] = h[s]*dA + du * row[12 + s];
          y += h[s] * row[28 + s];
        }
        y += uv * Dv;
        float zv = bf2f(sm.z[t*DINP + d]);
        sm.z[t*DINP + d] = f2bf(y * (zv * sigmoid_f(zv)));
      }
    }
  }
  __syncthreads();

  // ---- P6: out_proj via MFMA, round-5 operand order (Y as A, W as B) ----
  // D[m=t][n=out-channel]: lane = 16 consecutive channels at row t=quad*4+r.
  // Global epilogue: 4 B/lane, 4 segments/instruction — measured exact WRITE_SIZE.
  {
    f32x4 acc[2];
    acc[0] = (f32x4)0.f; acc[1] = (f32x4)0.f;
    #pragma unroll
    for (int kt = 0; kt < KT_OUT; ++kt) {
      short8 yfr = *(const short8*)(sm.z + l16*DINP + kt*32 + quad*8);
      #pragma unroll
      for (int i = 0; i < 2; ++i) {
        int ntg = wid*2 + i;
        short8 wfr = *(const short8*)(ws + OFF_OUT + ((ntg*KT_OUT + kt)*64 + lane)*8);
        acc[i] = __builtin_amdgcn_mfma_f32_16x16x32_bf16(yfr, wfr, acc[i], 0, 0, 0);
      }
    }
    #pragma unroll
    for (int i = 0; i < 2; ++i) {
      int col = (wid*2 + i)*16 + l16;
      #pragma unroll
      for (int r = 0; r < 4; ++r) {
        int row = quad*4 + r;
        int gi = ((b*TDIM + row)*HW784 + hw)*CDIM + col;
        float o = ldg<B16>(x, gi) + acc[i][r];
        stg<B16>(out, gi, o);
      }
    }
  }
}

__launch_bounds__(384, 6)   // 6 waves/EU -> 4 blocks/CU; caps VGPR at ~85
__global__ void mamba_mfma(
    const void* __restrict__ x,        const void* __restrict__ norm_w,
    const void* __restrict__ conv_w,   const void* __restrict__ conv_b,
    const void* __restrict__ dt_w,     const void* __restrict__ dt_b,
    const void* __restrict__ A_log,    const void* __restrict__ Dp,
    void* __restrict__ out)
{
  __shared__ Smem sm;
  if (probe_bf16(x))
    body<true >(sm, x, norm_w, conv_w, conv_b, dt_w, dt_b, A_log, Dp, out);
  else
    body<false>(sm, x, norm_w, conv_w, conv_b, dt_w, dt_b, A_log, Dp, out);
}

extern "C" void kernel_launch(void* const* d_in, const int* in_sizes, int n_in,
                              void* d_out, int out_size, void* d_ws, size_t ws_size,
                              hipStream_t stream) {
  pack_w<<<(PACK_TOT + 255) / 256, 256, 0, stream>>>(
      d_in[0], d_in[2], d_in[10], d_in[5]);
  mamba_mfma<<<NSEQ, 384, 0, stream>>>(
      d_in[0], d_in[1], d_in[3], d_in[4],
      d_in[6], d_in[7], d_in[8], d_in[9], d_out);
}

// Round 9
// 176.984 us; speedup vs baseline: 1.1674x; 1.1335x over previous
//
#include <hip/hip_runtime.h>

// TemporalMambaBlock: B=2,T=16,H=W=28,C=192; D_inner=384, d_state=16, dt_rank=12, d_conv=4
#define NSEQ 1568
#define TDIM 16
#define CDIM 192
#define DIN  384
#define SDIM 16
#define RNK  12
#define XZW  768
#define DBLW 44
#define HW784 784

// padded LDS strides (halves): row stride dwords mod 32 == 4 -> b128 quad reads 2-way (free)
#define XNP  200   // xn rows (192 + 8 pad)
#define DINP 392   // u / z rows (384 + 8)
#define DBLP 48    // dbl rows (44 -> 48, f32)

// packed-weight tiling. Fragment layout (lane, j=0..7):
//   packed[((nt*KT + kt)*64 + lane)*8 + j] = W[kt*32 + (lane>>4)*8 + j][nt*16 + (lane&15)]
// Operand-symmetric: usable as B (B[k=quad*8+j][n=l16]) or as A (A[m=l16][k=quad*8+j] = W^T).
#define NT_IN 48
#define KT_IN 6
#define NT_OUT 12
#define KT_OUT 12
#define NT_XP 3
#define KT_XP 12
#define GRP_IN  (NT_IN*KT_IN*64)    // 18432 groups of 8
#define GRP_OUT (NT_OUT*KT_OUT*64)  // 9216
#define GRP_XP  (NT_XP*KT_XP*64)    // 2304
#define OFF_OUT (GRP_IN*8)
#define OFF_XP  (OFF_OUT + GRP_OUT*8)
#define WS_ELEMS (OFF_XP + GRP_XP*8)            // 239616 u16
#define WS_NEED ((size_t)WS_ELEMS * 2)          // 479232 bytes

#define IN_EL  (CDIM*XZW)   // 147456
#define OUT_EL (DIN*CDIM)   // 73728
#define XP_EL  (GRP_XP*8)   // 18432 (packed space, incl. pad)
#define PACK_TOT (IN_EL + OUT_EL + XP_EL)

typedef unsigned short u16;
typedef unsigned int   u32;
typedef __attribute__((ext_vector_type(8))) short short8;
typedef __attribute__((ext_vector_type(4))) float f32x4;
typedef __attribute__((ext_vector_type(2))) unsigned int u32x2;

#define LOG2E 1.44269504f
#define LN2   0.69314718f

// fallback home for packed weights (rounds 7/8 proved correctness of this path,
// but it costs ~+115 MB HBM traffic/call vs d_ws — use only if ws too small).
__device__ __align__(16) u16 g_ws[WS_ELEMS];

__device__ __forceinline__ float bf2f(u16 u) {
  union { u32 i; float f; } c; c.i = ((u32)u) << 16; return c.f;
}
__device__ __forceinline__ u16 f2bf(float f) {   // round-to-nearest-even
  union { float f; u32 i; } c; c.f = f;
  u32 i = c.i;
  i += 0x7FFFu + ((i >> 16) & 1u);
  return (u16)(i >> 16);
}

__device__ __forceinline__ float ex2(float x) {
#if __has_builtin(__builtin_amdgcn_exp2f)
  return __builtin_amdgcn_exp2f(x);
#else
  return exp2f(x);
#endif
}
__device__ __forceinline__ float lg2(float x) {
#if __has_builtin(__builtin_amdgcn_logf)
  return __builtin_amdgcn_logf(x);
#else
  return log2f(x);
#endif
}
__device__ __forceinline__ float frcp(float x) {
#if __has_builtin(__builtin_amdgcn_rcpf)
  return __builtin_amdgcn_rcpf(x);
#else
  return 1.0f / x;
#endif
}
__device__ __forceinline__ float sigmoid_f(float s) {       // 1/(1+e^-s)
  return frcp(1.0f + ex2(-LOG2E * s));
}
__device__ __forceinline__ float softplus_f(float a) {      // log(1+e^a), stable
  return fmaxf(a, 0.f) + LN2 * lg2(1.0f + ex2(-LOG2E * fabsf(a)));
}

template<bool B16>
__device__ __forceinline__ float ldg(const void* p, int i) {
  if (B16) return bf2f(((const u16*)p)[i]);
  return ((const float*)p)[i];
}
template<bool B16>
__device__ __forceinline__ void stg(void* p, int i, float v) {
  if (B16) ((u16*)p)[i] = f2bf(v);
  else     ((float*)p)[i] = v;
}

// dtype probe: bf16 data has plausible exponents at even u16 slots; f32 read
// as u16 gives mantissa noise. (Rounds 2-8: selects the f32 path.)
__device__ __forceinline__ bool probe_bf16(const void* x) {
  const u16* xu = (const u16*)x;
  int plaus = 0;
  #pragma unroll
  for (int k = 0; k < 32; ++k) {
    u16 v = xu[2*k];
    int e = (v >> 7) & 0xFF;
    plaus += ((e >= 100 && e <= 140) || v == 0) ? 1 : 0;
  }
  return plaus >= 16;
}

// ---------------- weight packing: element-wise, coalesced reads -------------
template<bool B16>
__device__ __forceinline__ void pack_body(u16* __restrict__ ws,
                                          const void* in_w, const void* out_w,
                                          const void* xp_w, int e) {
  if (e < IN_EL) {
    int k = e / XZW, n = e - k*XZW;
    int nt = n >> 4, l16 = n & 15, kt = k >> 5, q8 = (k & 31) >> 3, j = k & 7;
    int lane = q8*16 + l16;
    ws[((nt*KT_IN + kt)*64 + lane)*8 + j] = f2bf(ldg<B16>(in_w, e));
  } else if (e < IN_EL + OUT_EL) {
    int ee = e - IN_EL;
    int k = ee / CDIM, n = ee - k*CDIM;
    int nt = n >> 4, l16 = n & 15, kt = k >> 5, q8 = (k & 31) >> 3, j = k & 7;
    int lane = q8*16 + l16;
    ws[OFF_OUT + ((nt*KT_OUT + kt)*64 + lane)*8 + j] = f2bf(ldg<B16>(out_w, ee));
  } else if (e < PACK_TOT) {             // xp: iterate packed space (handles pad)
    int ee = e - IN_EL - OUT_EL;
    int gg = ee >> 3, j = ee & 7;
    int lane = gg & 63, kt = (gg >> 6) % KT_XP, nt = gg / (64*KT_XP);
    int k = kt*32 + (lane >> 4)*8 + j, n = nt*16 + (lane & 15);
    ws[OFF_XP + ee] = f2bf(n < DBLW ? ldg<B16>(xp_w, k*DBLW + n) : 0.f);
  }
}

__global__ void pack_w(u16* __restrict__ ws,
                       const void* __restrict__ x, const void* __restrict__ in_w,
                       const void* __restrict__ out_w, const void* __restrict__ xp_w) {
  int e = blockIdx.x * blockDim.x + threadIdx.x;
  if (e < PACK_TOT) {
    if (probe_bf16(x)) pack_body<true >(ws, in_w, out_w, xp_w, e);
    else               pack_body<false>(ws, in_w, out_w, xp_w, e);
  }
}

__global__ void pack_w_g(const void* __restrict__ x, const void* __restrict__ in_w,
                         const void* __restrict__ out_w, const void* __restrict__ xp_w) {
  int e = blockIdx.x * blockDim.x + threadIdx.x;
  if (e < PACK_TOT) {
    if (probe_bf16(x)) pack_body<true >(g_ws, in_w, out_w, xp_w, e);
    else               pack_body<false>(g_ws, in_w, out_w, xp_w, e);
  }
}

// ---------------- fused MFMA kernel -----------------------------------------
struct Smem {
  float dbl[TDIM*DBLP];   // x_proj out: dt_low|B|C        3072 B
  u16   xn [TDIM*XNP];    // rmsnormed, padded             6400 B
  u16   u  [TDIM*DINP];   // u -> uc (in-place), padded   12544 B
  u16   z  [TDIM*DINP];   // z -> gated y (in-place)      12544 B
};                        // total 34,560 B -> 4 blocks/CU

template<bool B16>
__device__ __forceinline__ void body(
    Smem& sm, const u16* __restrict__ ws,
    const void* __restrict__ x,        const void* __restrict__ norm_w,
    const void* __restrict__ conv_w,   const void* __restrict__ conv_b,
    const void* __restrict__ dt_proj_w,const void* __restrict__ dt_proj_b,
    const void* __restrict__ A_log,    const void* __restrict__ Dp,
    void* __restrict__ out)
{
  const int tid  = threadIdx.x;
  const int wid  = tid >> 6;
  const int lane = tid & 63;
  const int quad = lane >> 4;
  const int l16  = lane & 15;
  const int n  = blockIdx.x;
  const int b  = n / HW784;
  const int hw = n - b * HW784;

  // ---- P1: RMSNorm straight from global (192 = 3 x 64 lanes) -> xn ----
  {
    const int c0 = lane, c1 = lane + 64, c2 = lane + 128;
    float nw0 = ldg<B16>(norm_w, c0), nw1 = ldg<B16>(norm_w, c1), nw2 = ldg<B16>(norm_w, c2);
    for (int t = wid; t < TDIM; t += 6) {
      int base = ((b*TDIM + t)*HW784 + hw)*CDIM;
      float v0 = ldg<B16>(x, base + c0);
      float v1 = ldg<B16>(x, base + c1);
      float v2 = ldg<B16>(x, base + c2);
      float ss = v0*v0 + v1*v1 + v2*v2;
      #pragma unroll
      for (int off = 32; off > 0; off >>= 1) ss += __shfl_xor(ss, off, 64);
      float rs = rsqrtf(ss * (1.0f/CDIM) + 1e-6f);
      sm.xn[t*XNP + c0] = f2bf(v0 * rs * nw0);
      sm.xn[t*XNP + c1] = f2bf(v1 * rs * nw1);
      sm.xn[t*XNP + c2] = f2bf(v2 * rs * nw2);
    }
  }
  __syncthreads();

  // ---- P2: in_proj via MFMA, swapped operands (W^T as A, Xn^T as B) ----
  // D[m=channel][n=t]: lane holds 4 consecutive channels at t=l16 -> b64 LDS write.
  {
    short8 xfr[KT_IN];   // B operand: Xn[t=l16][kt*32+quad*8..+7]
    #pragma unroll
    for (int kt = 0; kt < KT_IN; ++kt)
      xfr[kt] = *(const short8*)(sm.xn + l16*XNP + kt*32 + quad*8);
    #pragma unroll
    for (int g = 0; g < 2; ++g) {
      f32x4 acc[4];
      #pragma unroll
      for (int i = 0; i < 4; ++i) acc[i] = (f32x4)0.f;
      #pragma unroll
      for (int kt = 0; kt < KT_IN; ++kt) {
        #pragma unroll
        for (int i = 0; i < 4; ++i) {
          int ntg = wid*8 + g*4 + i;
          short8 wfr = *(const short8*)(ws + ((ntg*KT_IN + kt)*64 + lane)*8);
          acc[i] = __builtin_amdgcn_mfma_f32_16x16x32_bf16(wfr, xfr[kt], acc[i], 0, 0, 0);
        }
      }
      #pragma unroll
      for (int i = 0; i < 4; ++i) {
        int ntg = wid*8 + g*4 + i;
        u16* dst  = (ntg < 24) ? sm.u : sm.z;
        int col0  = ((ntg < 24) ? ntg*16 : (ntg-24)*16) + quad*4;  // 4 consecutive channels
        u32x2 o;
        o[0] = ((u32)f2bf(acc[i][1]) << 16) | f2bf(acc[i][0]);
        o[1] = ((u32)f2bf(acc[i][3]) << 16) | f2bf(acc[i][2]);
        *(u32x2*)(dst + l16*DINP + col0) = o;    // t=l16 row, b64 write
      }
    }
  }
  __syncthreads();

  // ---- P3: causal depthwise conv (k=4) + SiLU; keep uc in registers ----
  float uvr[TDIM];
  {
    const int d = tid;
    float cw0 = ldg<B16>(conv_w, d*4+0), cw1 = ldg<B16>(conv_w, d*4+1);
    float cw2 = ldg<B16>(conv_w, d*4+2), cw3 = ldg<B16>(conv_w, d*4+3);
    float cbias = ldg<B16>(conv_b, d);
    float um1 = 0.f, um2 = 0.f, um3 = 0.f;
    #pragma unroll
    for (int t = 0; t < TDIM; ++t) {
      float cur = bf2f(sm.u[t*DINP + d]);
      float s = cbias + cur*cw3 + um1*cw2 + um2*cw1 + um3*cw0;
      um3 = um2; um2 = um1; um1 = cur;
      float v = s * sigmoid_f(s);
      uvr[t] = v;
      sm.u[t*DINP + d] = f2bf(v);   // for P4 B-fragments
    }
  }

  // hoist scan parameters (round-5 placement: waves 3..5 idle in P4 overlap these)
  float wd[RNK];
  float dt_bias = ldg<B16>(dt_proj_b, tid);
  #pragma unroll
  for (int r = 0; r < RNK; ++r) wd[r] = ldg<B16>(dt_proj_w, r*DIN + tid);
  float Dv = ldg<B16>(Dp, tid);
  // geometric-A detection: A[s] = -exp(A_log[s]); geo iff A[s] == (s+1)*A[0]
  float a2 = -LOG2E * ex2(LOG2E * ldg<B16>(A_log, tid*SDIM + 0));  // LOG2E*A[0]
  bool geo = true;
  #pragma unroll
  for (int s = 1; s < SDIM; ++s) {
    float as = -LOG2E * ex2(LOG2E * ldg<B16>(A_log, tid*SDIM + s));
    geo = geo && (fabsf(as - (float)(s+1)*a2) <= 1e-4f * fabsf(as) + 1e-30f);
  }
  __syncthreads();

  // ---- P4: x_proj via MFMA, swapped operands (xp_w^T as A, uc^T as B) ----
  if (wid < 3) {
    f32x4 acc = (f32x4)0.f;
    #pragma unroll
    for (int kt = 0; kt < KT_XP; ++kt) {
      short8 ufr = *(const short8*)(sm.u + l16*DINP + kt*32 + quad*8);
      short8 wfr = *(const short8*)(ws + OFF_XP + ((wid*KT_XP + kt)*64 + lane)*8);
      acc = __builtin_amdgcn_mfma_f32_16x16x32_bf16(wfr, ufr, acc, 0, 0, 0);
    }
    // dbl[t=l16][feat = wid*16 + quad*4 + r]: 4 consecutive f32 -> b128 write
    *(f32x4*)(sm.dbl + l16*DBLP + wid*16 + quad*4) = acc;
  }
  __syncthreads();

  // ---- P5: dt_proj + softplus + selective scan + D skip + SiLU(z) gating ----
  {
    const int d = tid;
    float h[SDIM];
    #pragma unroll
    for (int s = 0; s < SDIM; ++s) h[s] = 0.f;
    if (geo) {
      for (int t = 0; t < TDIM; ++t) {
        const float* row = sm.dbl + t*DBLP;
        f32x4 d0 = *(const f32x4*)(row + 0);
        f32x4 d1 = *(const f32x4*)(row + 4);
        f32x4 d2 = *(const f32x4*)(row + 8);
        float a = dt_bias
          + d0[0]*wd[0] + d0[1]*wd[1] + d0[2]*wd[2]  + d0[3]*wd[3]
          + d1[0]*wd[4] + d1[1]*wd[5] + d1[2]*wd[6]  + d1[3]*wd[7]
          + d2[0]*wd[8] + d2[1]*wd[9] + d2[2]*wd[10] + d2[3]*wd[11];
        float dtv = softplus_f(a);
        float uv  = uvr[t];
        float du  = dtv * uv;
        float q = ex2(dtv * a2);               // dA[0] = exp(dt*A[0])
        float Pq[SDIM];                        // Pq[s] = q^(s+1), log-depth tree
        Pq[0] = q;        Pq[1] = q*q;         Pq[2] = Pq[1]*q;     Pq[3] = Pq[1]*Pq[1];
        Pq[4] = Pq[3]*q;  Pq[5] = Pq[3]*Pq[1]; Pq[6] = Pq[3]*Pq[2]; Pq[7] = Pq[3]*Pq[3];
        Pq[8] = Pq[7]*q;  Pq[9] = Pq[7]*Pq[1]; Pq[10]= Pq[7]*Pq[2]; Pq[11]= Pq[7]*Pq[3];
        Pq[12]= Pq[7]*Pq[4]; Pq[13]= Pq[7]*Pq[5]; Pq[14]= Pq[7]*Pq[6]; Pq[15]= Pq[7]*Pq[7];
        float y = 0.f;
        #pragma unroll
        for (int g = 0; g < 4; ++g) {
          f32x4 Bv = *(const f32x4*)(row + 12 + 4*g);
          f32x4 Cv = *(const f32x4*)(row + 28 + 4*g);
          #pragma unroll
          for (int j = 0; j < 4; ++j) {
            int s = 4*g + j;
            h[s] = h[s]*Pq[s] + du*Bv[j];
            y += h[s]*Cv[j];
          }
        }
        y += uv * Dv;
        float zv = bf2f(sm.z[t*DINP + d]);
        sm.z[t*DINP + d] = f2bf(y * (zv * sigmoid_f(zv)));
      }
    } else {
      // cold path (A_log not geometric): reloads A each step
      for (int t = 0; t < TDIM; ++t) {
        const float* row = sm.dbl + t*DBLP;
        float a = dt_bias;
        #pragma unroll
        for (int r = 0; r < RNK; ++r) a += row[r] * wd[r];
        float dtv = softplus_f(a);
        float uv  = uvr[t];
        float du  = dtv * uv;
        float y = 0.f;
        #pragma unroll
        for (int s = 0; s < SDIM; ++s) {
          float As = -LOG2E * ex2(LOG2E * ldg<B16>(A_log, d*SDIM + s));
          float dA = ex2(dtv * As);
          h[s] = h[s]*dA + du * row[12 + s];
          y += h[s] * row[28 + s];
        }
        y += uv * Dv;
        float zv = bf2f(sm.z[t*DINP + d]);
        sm.z[t*DINP + d] = f2bf(y * (zv * sigmoid_f(zv)));
      }
    }
  }
  __syncthreads();

  // ---- P6: out_proj via MFMA, round-5 operand order (Y as A, W as B) ----
  // D[m=t][n=out-channel]; epilogue 4 B/lane, 4 segments/instruction (proven clean).
  {
    f32x4 acc[2];
    acc[0] = (f32x4)0.f; acc[1] = (f32x4)0.f;
    #pragma unroll
    for (int kt = 0; kt < KT_OUT; ++kt) {
      short8 yfr = *(const short8*)(sm.z + l16*DINP + kt*32 + quad*8);
      #pragma unroll
      for (int i = 0; i < 2; ++i) {
        int ntg = wid*2 + i;
        short8 wfr = *(const short8*)(ws + OFF_OUT + ((ntg*KT_OUT + kt)*64 + lane)*8);
        acc[i] = __builtin_amdgcn_mfma_f32_16x16x32_bf16(yfr, wfr, acc[i], 0, 0, 0);
      }
    }
    #pragma unroll
    for (int i = 0; i < 2; ++i) {
      int col = (wid*2 + i)*16 + l16;
      #pragma unroll
      for (int r = 0; r < 4; ++r) {
        int row = quad*4 + r;
        int gi = ((b*TDIM + row)*HW784 + hw)*CDIM + col;
        float o = ldg<B16>(x, gi) + acc[i][r];
        stg<B16>(out, gi, o);
      }
    }
  }
}

__launch_bounds__(384, 6)   // 6 waves/EU -> 4 blocks/CU; caps VGPR at ~85
__global__ void mamba_mfma(
    const u16* __restrict__ ws,
    const void* __restrict__ x,        const void* __restrict__ norm_w,
    const void* __restrict__ conv_w,   const void* __restrict__ conv_b,
    const void* __restrict__ dt_w,     const void* __restrict__ dt_b,
    const void* __restrict__ A_log,    const void* __restrict__ Dp,
    void* __restrict__ out)
{
  __shared__ Smem sm;
  if (probe_bf16(x))
    body<true >(sm, ws, x, norm_w, conv_w, conv_b, dt_w, dt_b, A_log, Dp, out);
  else
    body<false>(sm, ws, x, norm_w, conv_w, conv_b, dt_w, dt_b, A_log, Dp, out);
}

__launch_bounds__(384, 6)
__global__ void mamba_mfma_g(
    const void* __restrict__ x,        const void* __restrict__ norm_w,
    const void* __restrict__ conv_w,   const void* __restrict__ conv_b,
    const void* __restrict__ dt_w,     const void* __restrict__ dt_b,
    const void* __restrict__ A_log,    const void* __restrict__ Dp,
    void* __restrict__ out)
{
  __shared__ Smem sm;
  if (probe_bf16(x))
    body<true >(sm, g_ws, x, norm_w, conv_w, conv_b, dt_w, dt_b, A_log, Dp, out);
  else
    body<false>(sm, g_ws, x, norm_w, conv_w, conv_b, dt_w, dt_b, A_log, Dp, out);
}

extern "C" void kernel_launch(void* const* d_in, const int* in_sizes, int n_in,
                              void* d_out, int out_size, void* d_ws, size_t ws_size,
                              hipStream_t stream) {
  if (ws_size >= WS_NEED) {
    pack_w<<<(PACK_TOT + 255) / 256, 256, 0, stream>>>(
        (u16*)d_ws, d_in[0], d_in[2], d_in[10], d_in[5]);
    mamba_mfma<<<NSEQ, 384, 0, stream>>>(
        (const u16*)d_ws,
        d_in[0], d_in[1], d_in[3], d_in[4],
        d_in[6], d_in[7], d_in[8], d_in[9], d_out);
  } else {
    pack_w_g<<<(PACK_TOT + 255) / 256, 256, 0, stream>>>(
        d_in[0], d_in[2], d_in[10], d_in[5]);
    mamba_mfma_g<<<NSEQ, 384, 0, stream>>>(
        d_in[0], d_in[1], d_in[3], d_in[4],
        d_in[6], d_in[7], d_in[8], d_in[9], d_out);
  }
}

// Round 10
// 173.592 us; speedup vs baseline: 1.1902x; 1.0195x over previous
//
#include <hip/hip_runtime.h>

// TemporalMambaBlock: B=2,T=16,H=W=28,C=192; D_inner=384, d_state=16, dt_rank=12, d_conv=4
#define NSEQ 1568
#define TDIM 16
#define CDIM 192
#define DIN  384
#define SDIM 16
#define RNK  12
#define XZW  768
#define DBLW 44
#define HW784 784

// padded LDS strides (halves): row stride dwords mod 32 == 4 -> b128 quad reads 2-way (free)
#define XNP  200   // xn rows (192 + 8 pad)
#define DINP 392   // u / z rows (384 + 8)
#define DBLP 48    // dbl rows (44 -> 48, f32)

// packed-weight tiling. Fragment layout (lane, j=0..7):
//   packed[((nt*KT + kt)*64 + lane)*8 + j] = W[kt*32 + (lane>>4)*8 + j][nt*16 + (lane&15)]
// Operand-symmetric: usable as B (B[k=quad*8+j][n=l16]) or as A (A[m=l16][k=quad*8+j] = W^T).
#define NT_IN 48
#define KT_IN 6
#define NT_OUT 12
#define KT_OUT 12
#define NT_XP 3
#define KT_XP 12
#define GRP_IN  (NT_IN*KT_IN*64)    // 18432 groups of 8
#define GRP_OUT (NT_OUT*KT_OUT*64)  // 9216
#define GRP_XP  (NT_XP*KT_XP*64)    // 2304
#define OFF_OUT (GRP_IN*8)
#define OFF_XP  (OFF_OUT + GRP_OUT*8)
#define WS_ELEMS (OFF_XP + GRP_XP*8)            // 239616 u16
#define WS_NEED ((size_t)WS_ELEMS * 2)          // 479232 bytes

#define IN_EL  (CDIM*XZW)   // 147456
#define OUT_EL (DIN*CDIM)   // 73728
#define XP_EL  (GRP_XP*8)   // 18432 (packed space, incl. pad)
#define PACK_TOT (IN_EL + OUT_EL + XP_EL)

typedef unsigned short u16;
typedef unsigned int   u32;
typedef __attribute__((ext_vector_type(8))) short short8;
typedef __attribute__((ext_vector_type(4))) float f32x4;
typedef __attribute__((ext_vector_type(2))) unsigned int u32x2;

#define LOG2E 1.44269504f
#define LN2   0.69314718f

// fallback home for packed weights (correct but ~+100 MB HBM/call vs d_ws —
// measured rounds 7/8; use only if ws too small).
__device__ __align__(16) u16 g_ws[WS_ELEMS];

__device__ __forceinline__ float bf2f(u16 u) {
  union { u32 i; float f; } c; c.i = ((u32)u) << 16; return c.f;
}
__device__ __forceinline__ u16 f2bf(float f) {   // round-to-nearest-even
  union { float f; u32 i; } c; c.f = f;
  u32 i = c.i;
  i += 0x7FFFu + ((i >> 16) & 1u);
  return (u16)(i >> 16);
}

__device__ __forceinline__ float ex2(float x) {
#if __has_builtin(__builtin_amdgcn_exp2f)
  return __builtin_amdgcn_exp2f(x);
#else
  return exp2f(x);
#endif
}
__device__ __forceinline__ float lg2(float x) {
#if __has_builtin(__builtin_amdgcn_logf)
  return __builtin_amdgcn_logf(x);
#else
  return log2f(x);
#endif
}
__device__ __forceinline__ float frcp(float x) {
#if __has_builtin(__builtin_amdgcn_rcpf)
  return __builtin_amdgcn_rcpf(x);
#else
  return 1.0f / x;
#endif
}
__device__ __forceinline__ float sigmoid_f(float s) {       // 1/(1+e^-s)
  return frcp(1.0f + ex2(-LOG2E * s));
}
__device__ __forceinline__ float softplus_f(float a) {      // log(1+e^a), stable
  return fmaxf(a, 0.f) + LN2 * lg2(1.0f + ex2(-LOG2E * fabsf(a)));
}

template<bool B16>
__device__ __forceinline__ float ldg(const void* p, int i) {
  if (B16) return bf2f(((const u16*)p)[i]);
  return ((const float*)p)[i];
}
template<bool B16>
__device__ __forceinline__ void stg(void* p, int i, float v) {
  if (B16) ((u16*)p)[i] = f2bf(v);
  else     ((float*)p)[i] = v;
}

// dtype probe: bf16 data has plausible exponents at even u16 slots; f32 read
// as u16 gives mantissa noise. (Rounds 2-9: selects the f32 path.)
__device__ __forceinline__ bool probe_bf16(const void* x) {
  const u16* xu = (const u16*)x;
  int plaus = 0;
  #pragma unroll
  for (int k = 0; k < 32; ++k) {
    u16 v = xu[2*k];
    int e = (v >> 7) & 0xFF;
    plaus += ((e >= 100 && e <= 140) || v == 0) ? 1 : 0;
  }
  return plaus >= 16;
}

// ---------------- weight packing: element-wise, coalesced reads -------------
template<bool B16>
__device__ __forceinline__ void pack_body(u16* __restrict__ ws,
                                          const void* in_w, const void* out_w,
                                          const void* xp_w, int e) {
  if (e < IN_EL) {
    int k = e / XZW, n = e - k*XZW;
    int nt = n >> 4, l16 = n & 15, kt = k >> 5, q8 = (k & 31) >> 3, j = k & 7;
    int lane = q8*16 + l16;
    ws[((nt*KT_IN + kt)*64 + lane)*8 + j] = f2bf(ldg<B16>(in_w, e));
  } else if (e < IN_EL + OUT_EL) {
    int ee = e - IN_EL;
    int k = ee / CDIM, n = ee - k*CDIM;
    int nt = n >> 4, l16 = n & 15, kt = k >> 5, q8 = (k & 31) >> 3, j = k & 7;
    int lane = q8*16 + l16;
    ws[OFF_OUT + ((nt*KT_OUT + kt)*64 + lane)*8 + j] = f2bf(ldg<B16>(out_w, ee));
  } else if (e < PACK_TOT) {             // xp: iterate packed space (handles pad)
    int ee = e - IN_EL - OUT_EL;
    int gg = ee >> 3, j = ee & 7;
    int lane = gg & 63, kt = (gg >> 6) % KT_XP, nt = gg / (64*KT_XP);
    int k = kt*32 + (lane >> 4)*8 + j, n = nt*16 + (lane & 15);
    ws[OFF_XP + ee] = f2bf(n < DBLW ? ldg<B16>(xp_w, k*DBLW + n) : 0.f);
  }
}

__global__ void pack_w(u16* __restrict__ ws,
                       const void* __restrict__ x, const void* __restrict__ in_w,
                       const void* __restrict__ out_w, const void* __restrict__ xp_w) {
  int e = blockIdx.x * blockDim.x + threadIdx.x;
  if (e < PACK_TOT) {
    if (probe_bf16(x)) pack_body<true >(ws, in_w, out_w, xp_w, e);
    else               pack_body<false>(ws, in_w, out_w, xp_w, e);
  }
}

__global__ void pack_w_g(const void* __restrict__ x, const void* __restrict__ in_w,
                         const void* __restrict__ out_w, const void* __restrict__ xp_w) {
  int e = blockIdx.x * blockDim.x + threadIdx.x;
  if (e < PACK_TOT) {
    if (probe_bf16(x)) pack_body<true >(g_ws, in_w, out_w, xp_w, e);
    else               pack_body<false>(g_ws, in_w, out_w, xp_w, e);
  }
}

// ---------------- fused MFMA kernel -----------------------------------------
struct Smem {
  float dbl[TDIM*DBLP];   // x_proj out: dt_low|B|C        3072 B
  u16   xn [TDIM*XNP];    // rmsnormed, padded             6400 B
  u16   u  [TDIM*DINP];   // u -> uc (in-place), padded   12544 B
  u16   z  [TDIM*DINP];   // z -> gated y (in-place)      12544 B
};                        // total 34,560 B -> 4 blocks/CU

template<bool B16>
__device__ __forceinline__ void body(
    Smem& sm, const u16* __restrict__ ws,
    const void* __restrict__ x,        const void* __restrict__ norm_w,
    const void* __restrict__ conv_w,   const void* __restrict__ conv_b,
    const void* __restrict__ dt_proj_w,const void* __restrict__ dt_proj_b,
    const void* __restrict__ A_log,    const void* __restrict__ Dp,
    void* __restrict__ out)
{
  const int tid  = threadIdx.x;
  const int wid  = tid >> 6;
  const int lane = tid & 63;
  const int quad = lane >> 4;
  const int l16  = lane & 15;
  const int n  = blockIdx.x;
  const int b  = n / HW784;
  const int hw = n - b * HW784;

  // ---- P1: RMSNorm straight from global (192 = 3 x 64 lanes) -> xn ----
  {
    const int c0 = lane, c1 = lane + 64, c2 = lane + 128;
    float nw0 = ldg<B16>(norm_w, c0), nw1 = ldg<B16>(norm_w, c1), nw2 = ldg<B16>(norm_w, c2);
    for (int t = wid; t < TDIM; t += 6) {
      int base = ((b*TDIM + t)*HW784 + hw)*CDIM;
      float v0 = ldg<B16>(x, base + c0);
      float v1 = ldg<B16>(x, base + c1);
      float v2 = ldg<B16>(x, base + c2);
      float ss = v0*v0 + v1*v1 + v2*v2;
      #pragma unroll
      for (int off = 32; off > 0; off >>= 1) ss += __shfl_xor(ss, off, 64);
      float rs = rsqrtf(ss * (1.0f/CDIM) + 1e-6f);
      sm.xn[t*XNP + c0] = f2bf(v0 * rs * nw0);
      sm.xn[t*XNP + c1] = f2bf(v1 * rs * nw1);
      sm.xn[t*XNP + c2] = f2bf(v2 * rs * nw2);
    }
  }
  __syncthreads();

  // ---- P2: in_proj via MFMA, swapped operands (W^T as A, Xn^T as B) ----
  // D[m=channel][n=t]: lane holds 4 consecutive channels at t=l16 -> b64 LDS write.
  {
    short8 xfr[KT_IN];   // B operand: Xn[t=l16][kt*32+quad*8..+7]
    #pragma unroll
    for (int kt = 0; kt < KT_IN; ++kt)
      xfr[kt] = *(const short8*)(sm.xn + l16*XNP + kt*32 + quad*8);
    #pragma unroll
    for (int g = 0; g < 2; ++g) {
      f32x4 acc[4];
      #pragma unroll
      for (int i = 0; i < 4; ++i) acc[i] = (f32x4)0.f;
      #pragma unroll
      for (int kt = 0; kt < KT_IN; ++kt) {
        #pragma unroll
        for (int i = 0; i < 4; ++i) {
          int ntg = wid*8 + g*4 + i;
          short8 wfr = *(const short8*)(ws + ((ntg*KT_IN + kt)*64 + lane)*8);
          acc[i] = __builtin_amdgcn_mfma_f32_16x16x32_bf16(wfr, xfr[kt], acc[i], 0, 0, 0);
        }
      }
      #pragma unroll
      for (int i = 0; i < 4; ++i) {
        int ntg = wid*8 + g*4 + i;
        u16* dst  = (ntg < 24) ? sm.u : sm.z;
        int col0  = ((ntg < 24) ? ntg*16 : (ntg-24)*16) + quad*4;  // 4 consecutive channels
        u32x2 o;
        o[0] = ((u32)f2bf(acc[i][1]) << 16) | f2bf(acc[i][0]);
        o[1] = ((u32)f2bf(acc[i][3]) << 16) | f2bf(acc[i][2]);
        *(u32x2*)(dst + l16*DINP + col0) = o;    // t=l16 row, b64 write
      }
    }
  }
  __syncthreads();

  // ---- P3: causal depthwise conv (k=4) + SiLU, in place (no reg carry:
  //      uvr[16] carried across P4 spilled to scratch => +53 MB HBM, round 9) ----
  {
    const int d = tid;
    float cw0 = ldg<B16>(conv_w, d*4+0), cw1 = ldg<B16>(conv_w, d*4+1);
    float cw2 = ldg<B16>(conv_w, d*4+2), cw3 = ldg<B16>(conv_w, d*4+3);
    float cbias = ldg<B16>(conv_b, d);
    float um1 = 0.f, um2 = 0.f, um3 = 0.f;
    #pragma unroll
    for (int t = 0; t < TDIM; ++t) {
      float cur = bf2f(sm.u[t*DINP + d]);
      float s = cbias + cur*cw3 + um1*cw2 + um2*cw1 + um3*cw0;
      um3 = um2; um2 = um1; um1 = cur;
      sm.u[t*DINP + d] = f2bf(s * sigmoid_f(s));
    }
  }

  // hoist scan parameters (waves 3..5 idle in P4 overlap these loads)
  float wd[RNK];
  float dt_bias = ldg<B16>(dt_proj_b, tid);
  #pragma unroll
  for (int r = 0; r < RNK; ++r) wd[r] = ldg<B16>(dt_proj_w, r*DIN + tid);
  float Dv = ldg<B16>(Dp, tid);
  // geometric-A detection: A[s] = -exp(A_log[s]); geo iff A[s] == (s+1)*A[0]
  float a2 = -LOG2E * ex2(LOG2E * ldg<B16>(A_log, tid*SDIM + 0));  // LOG2E*A[0]
  bool geo = true;
  #pragma unroll
  for (int s = 1; s < SDIM; ++s) {
    float as = -LOG2E * ex2(LOG2E * ldg<B16>(A_log, tid*SDIM + s));
    geo = geo && (fabsf(as - (float)(s+1)*a2) <= 1e-4f * fabsf(as) + 1e-30f);
  }
  __syncthreads();

  // ---- P4: x_proj via MFMA, swapped operands (xp_w^T as A, uc^T as B) ----
  if (wid < 3) {
    f32x4 acc = (f32x4)0.f;
    #pragma unroll
    for (int kt = 0; kt < KT_XP; ++kt) {
      short8 ufr = *(const short8*)(sm.u + l16*DINP + kt*32 + quad*8);
      short8 wfr = *(const short8*)(ws + OFF_XP + ((wid*KT_XP + kt)*64 + lane)*8);
      acc = __builtin_amdgcn_mfma_f32_16x16x32_bf16(wfr, ufr, acc, 0, 0, 0);
    }
    // dbl[t=l16][feat = wid*16 + quad*4 + r]: 4 consecutive f32 -> b128 write
    *(f32x4*)(sm.dbl + l16*DBLP + wid*16 + quad*4) = acc;
  }
  __syncthreads();

  // ---- P5: dt_proj + softplus + selective scan + D skip + SiLU(z) gating ----
  {
    const int d = tid;
    float h[SDIM];
    #pragma unroll
    for (int s = 0; s < SDIM; ++s) h[s] = 0.f;
    if (geo) {
      for (int t = 0; t < TDIM; ++t) {
        const float* row = sm.dbl + t*DBLP;
        f32x4 d0 = *(const f32x4*)(row + 0);
        f32x4 d1 = *(const f32x4*)(row + 4);
        f32x4 d2 = *(const f32x4*)(row + 8);
        float a = dt_bias
          + d0[0]*wd[0] + d0[1]*wd[1] + d0[2]*wd[2]  + d0[3]*wd[3]
          + d1[0]*wd[4] + d1[1]*wd[5] + d1[2]*wd[6]  + d1[3]*wd[7]
          + d2[0]*wd[8] + d2[1]*wd[9] + d2[2]*wd[10] + d2[3]*wd[11];
        float dtv = softplus_f(a);
        float uv  = bf2f(sm.u[t*DINP + d]);
        float du  = dtv * uv;
        float q = ex2(dtv * a2);               // dA[0] = exp(dt*A[0])
        float Pq[SDIM];                        // Pq[s] = q^(s+1), log-depth tree
        Pq[0] = q;        Pq[1] = q*q;         Pq[2] = Pq[1]*q;     Pq[3] = Pq[1]*Pq[1];
        Pq[4] = Pq[3]*q;  Pq[5] = Pq[3]*Pq[1]; Pq[6] = Pq[3]*Pq[2]; Pq[7] = Pq[3]*Pq[3];
        Pq[8] = Pq[7]*q;  Pq[9] = Pq[7]*Pq[1]; Pq[10]= Pq[7]*Pq[2]; Pq[11]= Pq[7]*Pq[3];
        Pq[12]= Pq[7]*Pq[4]; Pq[13]= Pq[7]*Pq[5]; Pq[14]= Pq[7]*Pq[6]; Pq[15]= Pq[7]*Pq[7];
        float y = 0.f;
        #pragma unroll
        for (int g = 0; g < 4; ++g) {
          f32x4 Bv = *(const f32x4*)(row + 12 + 4*g);
          f32x4 Cv = *(const f32x4*)(row + 28 + 4*g);
          #pragma unroll
          for (int j = 0; j < 4; ++j) {
            int s = 4*g + j;
            h[s] = h[s]*Pq[s] + du*Bv[j];
            y += h[s]*Cv[j];
          }
        }
        y += uv * Dv;
        float zv = bf2f(sm.z[t*DINP + d]);
        sm.z[t*DINP + d] = f2bf(y * (zv * sigmoid_f(zv)));
      }
    } else {
      // cold path (A_log not geometric): reloads A each step
      for (int t = 0; t < TDIM; ++t) {
        const float* row = sm.dbl + t*DBLP;
        float a = dt_bias;
        #pragma unroll
        for (int r = 0; r < RNK; ++r) a += row[r] * wd[r];
        float dtv = softplus_f(a);
        float uv  = bf2f(sm.u[t*DINP + d]);
        float du  = dtv * uv;
        float y = 0.f;
        #pragma unroll
        for (int s = 0; s < SDIM; ++s) {
          float As = -LOG2E * ex2(LOG2E * ldg<B16>(A_log, d*SDIM + s));
          float dA = ex2(dtv * As);
          h[s] = h[s]*dA + du * row[12 + s];
          y += h[s] * row[28 + s];
        }
        y += uv * Dv;
        float zv = bf2f(sm.z[t*DINP + d]);
        sm.z[t*DINP + d] = f2bf(y * (zv * sigmoid_f(zv)));
      }
    }
  }
  __syncthreads();

  // ---- P6: out_proj via MFMA, round-5 operand order (Y as A, W as B) ----
  // D[m=t][n=out-channel]; epilogue 4 B/lane, 4 segments/instruction (proven clean).
  {
    f32x4 acc[2];
    acc[0] = (f32x4)0.f; acc[1] = (f32x4)0.f;
    #pragma unroll
    for (int kt = 0; kt < KT_OUT; ++kt) {
      short8 yfr = *(const short8*)(sm.z + l16*DINP + kt*32 + quad*8);
      #pragma unroll
      for (int i = 0; i < 2; ++i) {
        int ntg = wid*2 + i;
        short8 wfr = *(const short8*)(ws + OFF_OUT + ((ntg*KT_OUT + kt)*64 + lane)*8);
        acc[i] = __builtin_amdgcn_mfma_f32_16x16x32_bf16(yfr, wfr, acc[i], 0, 0, 0);
      }
    }
    #pragma unroll
    for (int i = 0; i < 2; ++i) {
      int col = (wid*2 + i)*16 + l16;
      #pragma unroll
      for (int r = 0; r < 4; ++r) {
        int row = quad*4 + r;
        int gi = ((b*TDIM + row)*HW784 + hw)*CDIM + col;
        float o = ldg<B16>(x, gi) + acc[i][r];
        stg<B16>(out, gi, o);
      }
    }
  }
}

__launch_bounds__(384, 6)   // 6 waves/EU -> 4 blocks/CU; caps VGPR at ~85
__global__ void mamba_mfma(
    const u16* __restrict__ ws,
    const void* __restrict__ x,        const void* __restrict__ norm_w,
    const void* __restrict__ conv_w,   const void* __restrict__ conv_b,
    const void* __restrict__ dt_w,     const void* __restrict__ dt_b,
    const void* __restrict__ A_log,    const void* __restrict__ Dp,
    void* __restrict__ out)
{
  __shared__ Smem sm;
  if (probe_bf16(x))
    body<true >(sm, ws, x, norm_w, conv_w, conv_b, dt_w, dt_b, A_log, Dp, out);
  else
    body<false>(sm, ws, x, norm_w, conv_w, conv_b, dt_w, dt_b, A_log, Dp, out);
}

__launch_bounds__(384, 6)
__global__ void mamba_mfma_g(
    const void* __restrict__ x,        const void* __restrict__ norm_w,
    const void* __restrict__ conv_w,   const void* __restrict__ conv_b,
    const void* __restrict__ dt_w,     const void* __restrict__ dt_b,
    const void* __restrict__ A_log,    const void* __restrict__ Dp,
    void* __restrict__ out)
{
  __shared__ Smem sm;
  if (probe_bf16(x))
    body<true >(sm, g_ws, x, norm_w, conv_w, conv_b, dt_w, dt_b, A_log, Dp, out);
  else
    body<false>(sm, g_ws, x, norm_w, conv_w, conv_b, dt_w, dt_b, A_log, Dp, out);
}

extern "C" void kernel_launch(void* const* d_in, const int* in_sizes, int n_in,
                              void* d_out, int out_size, void* d_ws, size_t ws_size,
                              hipStream_t stream) {
  if (ws_size >= WS_NEED) {
    pack_w<<<(PACK_TOT + 255) / 256, 256, 0, stream>>>(
        (u16*)d_ws, d_in[0], d_in[2], d_in[10], d_in[5]);
    mamba_mfma<<<NSEQ, 384, 0, stream>>>(
        (const u16*)d_ws,
        d_in[0], d_in[1], d_in[3], d_in[4],
        d_in[6], d_in[7], d_in[8], d_in[9], d_out);
  } else {
    pack_w_g<<<(PACK_TOT + 255) / 256, 256, 0, stream>>>(
        d_in[0], d_in[2], d_in[10], d_in[5]);
    mamba_mfma_g<<<NSEQ, 384, 0, stream>>>(
        d_in[0], d_in[1], d_in[3], d_in[4],
        d_in[6], d_in[7], d_in[8], d_in[9], d_out);
  }
}